// Round 4
// baseline (2060.461 us; speedup 1.0000x reference)
//
#include <hip/hip_runtime.h>
#include <hip/hip_bf16.h>
#include <cstddef>

#define N_NODES 100000
#define F_IN    512
#define HID     64
#define NCLS    40

#define BUCK_SZ   128
#define NBUCK     ((N_NODES + BUCK_SZ - 1) / BUCK_SZ)   // 782
#define SRC_MASK  0x1FFFF                                // 17 bits

// ---------- utility ----------
__global__ void zero_kernel(int* __restrict__ p, int n) {
    int i = blockIdx.x * blockDim.x + threadIdx.x;
    if (i < n) p[i] = 0;
}

// ---------- degree / normalization ----------
__global__ void count_deg_kernel(const int* __restrict__ dst, int* __restrict__ cnt, int E) {
    int e = blockIdx.x * blockDim.x + threadIdx.x;
    if (e < E) atomicAdd(&cnt[dst[e]], 1);
}

__global__ void make_dinv_kernel(const int* __restrict__ cnt, float* __restrict__ dinv, int n) {
    int i = blockIdx.x * blockDim.x + threadIdx.x;
    if (i < n) dinv[i] = rsqrtf((float)(cnt[i] + 1));   // +1 self-loop
}

// ---------- bucket totals: bsum[b] = sum cnt[b*128 .. b*128+128) ----------
__global__ __launch_bounds__(128) void bucket_sum_kernel(const int* __restrict__ cnt,
                                                         int* __restrict__ bsum, int M) {
    __shared__ int sd[128];
    const int b = blockIdx.x, t = threadIdx.x;
    const int idx = b * BUCK_SZ + t;
    sd[t] = (idx < M) ? cnt[idx] : 0;
    __syncthreads();
    for (int d = 64; d > 0; d >>= 1) {
        if (t < d) sd[t] += sd[t + d];
        __syncthreads();
    }
    if (t == 0) bsum[b] = sd[0];
}

// ---------- exclusive scan over NBUCK (=782) bucket sums, one block ----------
__global__ __launch_bounds__(1024) void bucket_scan_kernel(const int* __restrict__ bsum,
                                                           int* __restrict__ boff,
                                                           int* __restrict__ bcur,
                                                           int nb, int E) {
    __shared__ int sd[1024];
    const int t = threadIdx.x;
    int v = (t < nb) ? bsum[t] : 0;
    sd[t] = v; __syncthreads();
    for (int d = 1; d < 1024; d <<= 1) {
        int u = (t >= d) ? sd[t - d] : 0;
        __syncthreads();
        sd[t] += u;
        __syncthreads();
    }
    if (t < nb) {
        int exc = sd[t] - v;
        boff[t] = exc;
        bcur[t] = exc;
    }
    if (t == 0) boff[nb] = E;
}

// ---------- bucket scatter: ebuf[pos] = src | (dst_local << 17) ----------
__global__ void scatter_bucket_kernel(const int* __restrict__ src, const int* __restrict__ dst,
                                      int* __restrict__ bcur,
                                      unsigned int* __restrict__ ebuf, int E) {
    int e = blockIdx.x * blockDim.x + threadIdx.x;
    if (e < E) {
        int d = dst[e];
        int b = d / BUCK_SZ;
        int pos = atomicAdd(&bcur[b], 1);
        ebuf[pos] = (unsigned int)src[e] | ((unsigned int)(d & (BUCK_SZ - 1)) << 17);
    }
}

// ---------- GEMM1: H1 = X (Mx512) @ W1 (512x64) ----------
#define BK 32
__global__ __launch_bounds__(256) void gemm1_kernel(const float* __restrict__ X,
                                                    const float* __restrict__ W,
                                                    float* __restrict__ H,
                                                    int M) {
    __shared__ float As[BK][68];
    __shared__ float Bs[BK][64];

    const int tid = threadIdx.x;
    const int tx = tid & 15;
    const int ty = tid >> 4;
    const int rowBase = blockIdx.x * 64;

    const int a_row = tid >> 3;
    const int a_q   = tid & 7;
    const int b_row = tid >> 4;
    const int b_c4  = tid & 15;

    float acc[4][4] = {};

    for (int kt = 0; kt < F_IN; kt += BK) {
        #pragma unroll
        for (int h = 0; h < 2; ++h) {
            int r = a_row + h * 32;
            int gr = rowBase + r;
            if (gr >= M) gr = M - 1;
            const float4 v = *reinterpret_cast<const float4*>(
                &X[(size_t)gr * F_IN + kt + a_q * 4]);
            As[a_q * 4 + 0][r] = v.x;
            As[a_q * 4 + 1][r] = v.y;
            As[a_q * 4 + 2][r] = v.z;
            As[a_q * 4 + 3][r] = v.w;
        }
        #pragma unroll
        for (int h = 0; h < 2; ++h) {
            int kr = b_row + h * 16;
            const float4 v = *reinterpret_cast<const float4*>(
                &W[(size_t)(kt + kr) * 64 + b_c4 * 4]);
            *reinterpret_cast<float4*>(&Bs[kr][b_c4 * 4]) = v;
        }
        __syncthreads();

        #pragma unroll
        for (int k = 0; k < BK; ++k) {
            const float4 a = *reinterpret_cast<const float4*>(&As[k][ty * 4]);
            const float4 b = *reinterpret_cast<const float4*>(&Bs[k][tx * 4]);
            acc[0][0] += a.x * b.x; acc[0][1] += a.x * b.y; acc[0][2] += a.x * b.z; acc[0][3] += a.x * b.w;
            acc[1][0] += a.y * b.x; acc[1][1] += a.y * b.y; acc[1][2] += a.y * b.z; acc[1][3] += a.y * b.w;
            acc[2][0] += a.z * b.x; acc[2][1] += a.z * b.y; acc[2][2] += a.z * b.z; acc[2][3] += a.z * b.w;
            acc[3][0] += a.w * b.x; acc[3][1] += a.w * b.y; acc[3][2] += a.w * b.z; acc[3][3] += a.w * b.w;
        }
        __syncthreads();
    }

    #pragma unroll
    for (int i = 0; i < 4; ++i) {
        int gr = rowBase + ty * 4 + i;
        if (gr < M) {
            float4 v = make_float4(acc[i][0], acc[i][1], acc[i][2], acc[i][3]);
            *reinterpret_cast<float4*>(&H[(size_t)gr * HID + tx * 4]) = v;
        }
    }
}

// ---------- bucketed aggregation: one block per 128-node bucket ----------
// tile[loc][lane] = sum over edges into node (bucket_base+loc) of h[src]*norm
//                   + self-loop h[node]*dinv[node]^2
// RELU=true: out = max(tile + bias, 0)
template<bool RELU>
__global__ __launch_bounds__(256) void agg_bucket_kernel(const float* __restrict__ h,
                                                         const unsigned int* __restrict__ ebuf,
                                                         const int* __restrict__ boff,
                                                         const float* __restrict__ dinv,
                                                         const float* __restrict__ bias,
                                                         float* __restrict__ out, int M) {
    __shared__ float tile[BUCK_SZ * HID];   // 32 KB
    __shared__ float ldinv[BUCK_SZ];

    const int tid  = threadIdx.x;
    const int lane = tid & 63;
    const int wid  = tid >> 6;              // wave 0..3
    const int b    = blockIdx.x;
    const int base = b * BUCK_SZ;

    if (tid < BUCK_SZ) {
        int node = base + tid;
        ldinv[tid] = (node < M) ? dinv[node] : 0.f;
    }
    __syncthreads();

    // init tile with self-loop contribution (coalesced h reads)
    for (int i = tid; i < BUCK_SZ * HID; i += 256) {
        int r = i >> 6;
        int node = base + r;
        float v = 0.f;
        if (node < M) {
            float di = ldinv[r];
            v = h[(size_t)node * HID + (i & 63)] * di * di;
        }
        tile[i] = v;
    }
    __syncthreads();

    const int e0 = boff[b], e1 = boff[b + 1];
    for (int ch = e0 + wid * 64; ch < e1; ch += 256) {
        unsigned int pk = 0;
        float nm = 0.f;
        const int cnt = min(64, e1 - ch);
        if (lane < cnt) {
            pk = ebuf[ch + lane];
            int s = pk & SRC_MASK;
            nm = dinv[s] * ldinv[pk >> 17];
        }
        int j = 0;
        for (; j + 4 <= cnt; j += 4) {
            unsigned int pa = __shfl(pk, j);
            unsigned int pb = __shfl(pk, j + 1);
            unsigned int pc = __shfl(pk, j + 2);
            unsigned int pd = __shfl(pk, j + 3);
            float na = __shfl(nm, j);
            float nb = __shfl(nm, j + 1);
            float nc = __shfl(nm, j + 2);
            float nd = __shfl(nm, j + 3);
            float va = h[(size_t)(pa & SRC_MASK) * HID + lane];
            float vb = h[(size_t)(pb & SRC_MASK) * HID + lane];
            float vc = h[(size_t)(pc & SRC_MASK) * HID + lane];
            float vd = h[(size_t)(pd & SRC_MASK) * HID + lane];
            atomicAdd(&tile[(pa >> 17) * HID + lane], va * na);
            atomicAdd(&tile[(pb >> 17) * HID + lane], vb * nb);
            atomicAdd(&tile[(pc >> 17) * HID + lane], vc * nc);
            atomicAdd(&tile[(pd >> 17) * HID + lane], vd * nd);
        }
        for (; j < cnt; ++j) {
            unsigned int p = __shfl(pk, j);
            float n = __shfl(nm, j);
            float v = h[(size_t)(p & SRC_MASK) * HID + lane];
            atomicAdd(&tile[(p >> 17) * HID + lane], v * n);
        }
    }
    __syncthreads();

    const float bval = RELU ? bias[lane] : 0.f;
    for (int i = tid; i < BUCK_SZ * HID; i += 256) {
        int node = base + (i >> 6);
        if (node < M) {
            float v = tile[i];
            if (RELU) v = fmaxf(v + bval, 0.f);
            out[(size_t)node * HID + (i & 63)] = v;
        }
    }
}

// ---------- GEMM2 (64->40) + b2 + log_softmax, fused ----------
__global__ __launch_bounds__(256) void gemm2_lsm_kernel(const float* __restrict__ A,
                                                        const float* __restrict__ W,
                                                        const float* __restrict__ b2,
                                                        float* __restrict__ out, int M) {
    __shared__ float ws[HID * NCLS];     // 64x40
    __shared__ float hs[32][68];
    __shared__ float h2[32][NCLS];
    __shared__ float stats[32][2];

    const int tid = threadIdx.x;
    const int rowBase = blockIdx.x * 32;

    for (int i = tid; i < HID * NCLS; i += 256) ws[i] = W[i];

    #pragma unroll
    for (int p = 0; p < 2; ++p) {
        int i = p * 256 + tid;           // 32 rows x 16 float4
        int r = i >> 4, c4 = i & 15;
        int gr = rowBase + r;
        float4 v = make_float4(0.f, 0.f, 0.f, 0.f);
        if (gr < M) v = *reinterpret_cast<const float4*>(&A[(size_t)gr * HID + c4 * 4]);
        *reinterpret_cast<float4*>(&hs[r][c4 * 4]) = v;
    }
    __syncthreads();

    #pragma unroll
    for (int p = 0; p < 5; ++p) {
        int o = p * 256 + tid;           // 32 x 40 = 1280
        int r = o / NCLS, j = o - r * NCLS;
        float s = b2[j];
        #pragma unroll
        for (int k = 0; k < HID; ++k) s += hs[r][k] * ws[k * NCLS + j];
        h2[r][j] = s;
    }
    __syncthreads();

    if (tid < 32) {
        float m = -1e30f;
        #pragma unroll
        for (int j = 0; j < NCLS; ++j) m = fmaxf(m, h2[tid][j]);
        float s = 0.f;
        #pragma unroll
        for (int j = 0; j < NCLS; ++j) s += expf(h2[tid][j] - m);
        stats[tid][0] = m;
        stats[tid][1] = logf(s);
    }
    __syncthreads();

    #pragma unroll
    for (int p = 0; p < 5; ++p) {
        int o = p * 256 + tid;
        int r = o / NCLS, j = o - r * NCLS;
        int gr = rowBase + r;
        if (gr < M) out[(size_t)gr * NCLS + j] = h2[r][j] - stats[r][0] - stats[r][1];
    }
}

extern "C" void kernel_launch(void* const* d_in, const int* in_sizes, int n_in,
                              void* d_out, int out_size, void* d_ws, size_t ws_size,
                              hipStream_t stream) {
    const float* x  = (const float*)d_in[0];
    const int*   ei = (const int*)d_in[1];
    const float* W1 = (const float*)d_in[2];
    const float* b1 = (const float*)d_in[3];
    const float* W2 = (const float*)d_in[4];
    const float* b2 = (const float*)d_in[5];
    float* out = (float*)d_out;

    const int M = N_NODES;
    const int E = in_sizes[1] / 2;
    const int* src = ei;
    const int* dst = ei + E;

    // ---- workspace layout (peak 58.43 MB, below the 58.84 MB proven-safe) ----
    char* ws = (char*)d_ws;
    int*          cnt  = (int*)         (ws + 0);          // 400 KB
    float*        dinv = (float*)       (ws + 409600);     // 400 KB
    int*          bsum = (int*)         (ws + 819200);     // ~3.1 KB
    int*          boff = (int*)         (ws + 823296);     // ~3.1 KB (NBUCK+1)
    int*          bcur = (int*)         (ws + 827392);     // ~3.1 KB
    unsigned int* ebuf = (unsigned int*)(ws + 831488);     // 6.4 MB  -> ends 7,231,488
    float*        h1   = (float*)       (ws + 7231488);    // 25.6 MB -> ends 32,831,488
    float*        z    = (float*)       (ws + 32831488);   // 25.6 MB -> ends 58,431,488
    float*        agg2 = h1;                                // alias: h1 dead after first agg

    zero_kernel<<<(M + 255) / 256, 256, 0, stream>>>(cnt, M);
    count_deg_kernel<<<(E + 255) / 256, 256, 0, stream>>>(dst, cnt, E);
    make_dinv_kernel<<<(M + 255) / 256, 256, 0, stream>>>(cnt, dinv, M);

    bucket_sum_kernel<<<NBUCK, 128, 0, stream>>>(cnt, bsum, M);
    bucket_scan_kernel<<<1, 1024, 0, stream>>>(bsum, boff, bcur, NBUCK, E);
    scatter_bucket_kernel<<<(E + 255) / 256, 256, 0, stream>>>(src, dst, bcur, ebuf, E);

    gemm1_kernel<<<(M + 63) / 64, 256, 0, stream>>>(x, W1, h1, M);

    agg_bucket_kernel<true><<<NBUCK, 256, 0, stream>>>(h1, ebuf, boff, dinv, b1, z, M);
    agg_bucket_kernel<false><<<NBUCK, 256, 0, stream>>>(z, ebuf, boff, dinv, nullptr, agg2, M);

    gemm2_lsm_kernel<<<(M + 31) / 32, 256, 0, stream>>>(agg2, W2, b2, out, M);
}

// Round 5
// 751.412 us; speedup vs baseline: 2.7421x; 2.7421x over previous
//
#include <hip/hip_runtime.h>
#include <hip/hip_bf16.h>
#include <cstddef>

#define N_NODES 100000
#define F_IN    512
#define HID     64
#define NCLS    40

#define BUCK_SZ   128
#define NBUCK     ((N_NODES + BUCK_SZ - 1) / BUCK_SZ)   // 782
#define SRC_MASK  0x1FFFF                                // 17 bits

// ---------- utility ----------
__global__ void zero_kernel(int* __restrict__ p, int n) {
    int i = blockIdx.x * blockDim.x + threadIdx.x;
    if (i < n) p[i] = 0;
}

// ---------- degree / normalization ----------
__global__ void count_deg_kernel(const int* __restrict__ dst, int* __restrict__ cnt, int E) {
    int e = blockIdx.x * blockDim.x + threadIdx.x;
    if (e < E) atomicAdd(&cnt[dst[e]], 1);
}

__global__ void make_dinv_kernel(const int* __restrict__ cnt, float* __restrict__ dinv, int n) {
    int i = blockIdx.x * blockDim.x + threadIdx.x;
    if (i < n) dinv[i] = rsqrtf((float)(cnt[i] + 1));   // +1 self-loop
}

// ---------- exclusive scan (2-level) over degree counts ----------
#define SCAN_ELEMS 1024   // elements per block

__global__ __launch_bounds__(256) void scan_partial_kernel(const int* __restrict__ cnt,
                                                           int* __restrict__ part, int M) {
    __shared__ int sd[256];
    const int b = blockIdx.x, t = threadIdx.x;
    const int base = b * SCAN_ELEMS;
    int s = 0;
    for (int i = t; i < SCAN_ELEMS; i += 256) {
        int idx = base + i;
        s += (idx < M) ? cnt[idx] : 0;
    }
    sd[t] = s; __syncthreads();
    for (int d = 128; d > 0; d >>= 1) {
        if (t < d) sd[t] += sd[t + d];
        __syncthreads();
    }
    if (t == 0) part[b] = sd[0];
}

__global__ void scan_single_kernel(int* __restrict__ part, int n) {
    __shared__ int sd[128];
    int t = threadIdx.x;
    int v = (t < n) ? part[t] : 0;
    sd[t] = v; __syncthreads();
    for (int d = 1; d < 128; d <<= 1) {
        int u = (t >= d) ? sd[t - d] : 0;
        __syncthreads();
        sd[t] += u;
        __syncthreads();
    }
    if (t < n) part[t] = sd[t] - v;   // exclusive
}

__global__ __launch_bounds__(256) void scan_final_kernel(const int* __restrict__ cnt,
                                                         const int* __restrict__ part,
                                                         int* __restrict__ off, int M) {
    __shared__ int sd[256];
    const int b = blockIdx.x, t = threadIdx.x;
    const int base = b * SCAN_ELEMS + t * 4;
    int cs[4];
    #pragma unroll
    for (int i = 0; i < 4; ++i) cs[i] = (base + i < M) ? cnt[base + i] : 0;
    const int tot = cs[0] + cs[1] + cs[2] + cs[3];
    sd[t] = tot; __syncthreads();
    for (int d = 1; d < 256; d <<= 1) {
        int u = (t >= d) ? sd[t - d] : 0;
        __syncthreads();
        sd[t] += u;
        __syncthreads();
    }
    int run = sd[t] - tot + part[b];
    #pragma unroll
    for (int i = 0; i < 4; ++i) {
        if (base + i < M) off[base + i] = run;
        run += cs[i];
    }
    if (base < M && base + 4 >= M) off[M] = run;   // total (trailing cs are 0)
}

// ---------- bucket cursors: bcur[b] = off[b*BUCK_SZ] ----------
__global__ void init_bcur_kernel(const int* __restrict__ off, int* __restrict__ bcur, int nb) {
    int i = blockIdx.x * blockDim.x + threadIdx.x;
    if (i < nb) bcur[i] = off[i * BUCK_SZ];
}

// ---------- phase 1: scatter edges into coarse dst-buckets ----------
__global__ void scatter_bucket_kernel(const int* __restrict__ src, const int* __restrict__ dst,
                                      int* __restrict__ bcur,
                                      unsigned int* __restrict__ ebuf, int E) {
    int e = blockIdx.x * blockDim.x + threadIdx.x;
    if (e < E) {
        int d = dst[e];
        int b = d / BUCK_SZ;
        int pos = atomicAdd(&bcur[b], 1);
        ebuf[pos] = (unsigned int)src[e] | ((unsigned int)(d & (BUCK_SZ - 1)) << 17);
    }
}

// ---------- phase 2: within-bucket counting place -> per-node CSR ----------
// bucket b's edges occupy [off[b*128], off[min(b*128+128,M)]) in BOTH ebuf
// (unordered) and csr_src (grouped by node) — writes stay in an 8KB window.
__global__ __launch_bounds__(256) void sort_bucket_kernel(const unsigned int* __restrict__ ebuf,
                                                          const int* __restrict__ off,
                                                          int* __restrict__ csr_src, int M) {
    __shared__ int lcur[BUCK_SZ];
    const int b = blockIdx.x, t = threadIdx.x;
    const int base = b * BUCK_SZ;
    if (t < BUCK_SZ) {
        int node = base + t;
        lcur[t] = (node <= M) ? off[min(node, M)] : 0;
    }
    __syncthreads();
    const int e0 = off[base];
    const int e1 = off[min(base + BUCK_SZ, M)];
    for (int e = e0 + t; e < e1; e += 256) {
        unsigned int pk = ebuf[e];
        int loc = pk >> 17;
        int pos = atomicAdd(&lcur[loc], 1);
        csr_src[pos] = (int)(pk & SRC_MASK);
    }
}

// ---------- GEMM1: H1 = X (Mx512) @ W1 (512x64) ----------
#define BK 32
__global__ __launch_bounds__(256) void gemm1_kernel(const float* __restrict__ X,
                                                    const float* __restrict__ W,
                                                    float* __restrict__ H,
                                                    int M) {
    __shared__ float As[BK][68];
    __shared__ float Bs[BK][64];

    const int tid = threadIdx.x;
    const int tx = tid & 15;
    const int ty = tid >> 4;
    const int rowBase = blockIdx.x * 64;

    const int a_row = tid >> 3;
    const int a_q   = tid & 7;
    const int b_row = tid >> 4;
    const int b_c4  = tid & 15;

    float acc[4][4] = {};

    for (int kt = 0; kt < F_IN; kt += BK) {
        #pragma unroll
        for (int h = 0; h < 2; ++h) {
            int r = a_row + h * 32;
            int gr = rowBase + r;
            if (gr >= M) gr = M - 1;
            const float4 v = *reinterpret_cast<const float4*>(
                &X[(size_t)gr * F_IN + kt + a_q * 4]);
            As[a_q * 4 + 0][r] = v.x;
            As[a_q * 4 + 1][r] = v.y;
            As[a_q * 4 + 2][r] = v.z;
            As[a_q * 4 + 3][r] = v.w;
        }
        #pragma unroll
        for (int h = 0; h < 2; ++h) {
            int kr = b_row + h * 16;
            const float4 v = *reinterpret_cast<const float4*>(
                &W[(size_t)(kt + kr) * 64 + b_c4 * 4]);
            *reinterpret_cast<float4*>(&Bs[kr][b_c4 * 4]) = v;
        }
        __syncthreads();

        #pragma unroll
        for (int k = 0; k < BK; ++k) {
            const float4 a = *reinterpret_cast<const float4*>(&As[k][ty * 4]);
            const float4 b = *reinterpret_cast<const float4*>(&Bs[k][tx * 4]);
            acc[0][0] += a.x * b.x; acc[0][1] += a.x * b.y; acc[0][2] += a.x * b.z; acc[0][3] += a.x * b.w;
            acc[1][0] += a.y * b.x; acc[1][1] += a.y * b.y; acc[1][2] += a.y * b.z; acc[1][3] += a.y * b.w;
            acc[2][0] += a.z * b.x; acc[2][1] += a.z * b.y; acc[2][2] += a.z * b.z; acc[2][3] += a.z * b.w;
            acc[3][0] += a.w * b.x; acc[3][1] += a.w * b.y; acc[3][2] += a.w * b.z; acc[3][3] += a.w * b.w;
        }
        __syncthreads();
    }

    #pragma unroll
    for (int i = 0; i < 4; ++i) {
        int gr = rowBase + ty * 4 + i;
        if (gr < M) {
            float4 v = make_float4(acc[i][0], acc[i][1], acc[i][2], acc[i][3]);
            *reinterpret_cast<float4*>(&H[(size_t)gr * HID + tx * 4]) = v;
        }
    }
}

// ---------- gather-based aggregation (one wave per node, width 64) ----------
template<bool RELU>
__global__ __launch_bounds__(256) void agg_gather_kernel(const float* __restrict__ h,
                                                         const int* __restrict__ off,
                                                         const int* __restrict__ csr_src,
                                                         const float* __restrict__ dinv,
                                                         const float* __restrict__ bias,
                                                         float* __restrict__ out, int M) {
    const int lane = threadIdx.x & 63;
    const int n = blockIdx.x * 4 + (threadIdx.x >> 6);
    if (n >= M) return;

    const float di = dinv[n];
    float acc = h[(size_t)n * HID + lane] * di * di;   // self-loop

    const int s0 = off[n], s1 = off[n + 1];
    for (int e = s0; e < s1; ) {
        int   s  = 0;
        float nm = 0.f;
        if (e + lane < s1) {
            s  = csr_src[e + lane];
            nm = dinv[s] * di;
        }
        const int cnt = min(64, s1 - e);
        int j = 0;
        for (; j + 4 <= cnt; j += 4) {
            int sa = __shfl(s, j);
            int sb = __shfl(s, j + 1);
            int sc = __shfl(s, j + 2);
            int sd = __shfl(s, j + 3);
            float na = __shfl(nm, j);
            float nb = __shfl(nm, j + 1);
            float nc = __shfl(nm, j + 2);
            float nd = __shfl(nm, j + 3);
            float va = h[(size_t)sa * HID + lane];
            float vb = h[(size_t)sb * HID + lane];
            float vc = h[(size_t)sc * HID + lane];
            float vd = h[(size_t)sd * HID + lane];
            acc = fmaf(va, na, acc);
            acc = fmaf(vb, nb, acc);
            acc = fmaf(vc, nc, acc);
            acc = fmaf(vd, nd, acc);
        }
        for (; j < cnt; ++j) {
            int sj = __shfl(s, j);
            float nj = __shfl(nm, j);
            acc = fmaf(h[(size_t)sj * HID + lane], nj, acc);
        }
        e += cnt;
    }

    if (RELU) acc = fmaxf(acc + bias[lane], 0.0f);
    out[(size_t)n * HID + lane] = acc;
}

// ---------- GEMM2 (64->40) + b2 + log_softmax, fused ----------
__global__ __launch_bounds__(256) void gemm2_lsm_kernel(const float* __restrict__ A,
                                                        const float* __restrict__ W,
                                                        const float* __restrict__ b2,
                                                        float* __restrict__ out, int M) {
    __shared__ float ws[HID * NCLS];     // 64x40
    __shared__ float hs[32][68];
    __shared__ float h2[32][NCLS];
    __shared__ float stats[32][2];

    const int tid = threadIdx.x;
    const int rowBase = blockIdx.x * 32;

    for (int i = tid; i < HID * NCLS; i += 256) ws[i] = W[i];

    #pragma unroll
    for (int p = 0; p < 2; ++p) {
        int i = p * 256 + tid;           // 32 rows x 16 float4
        int r = i >> 4, c4 = i & 15;
        int gr = rowBase + r;
        float4 v = make_float4(0.f, 0.f, 0.f, 0.f);
        if (gr < M) v = *reinterpret_cast<const float4*>(&A[(size_t)gr * HID + c4 * 4]);
        *reinterpret_cast<float4*>(&hs[r][c4 * 4]) = v;
    }
    __syncthreads();

    #pragma unroll
    for (int p = 0; p < 5; ++p) {
        int o = p * 256 + tid;           // 32 x 40 = 1280
        int r = o / NCLS, j = o - r * NCLS;
        float s = b2[j];
        #pragma unroll
        for (int k = 0; k < HID; ++k) s += hs[r][k] * ws[k * NCLS + j];
        h2[r][j] = s;
    }
    __syncthreads();

    if (tid < 32) {
        float m = -1e30f;
        #pragma unroll
        for (int j = 0; j < NCLS; ++j) m = fmaxf(m, h2[tid][j]);
        float s = 0.f;
        #pragma unroll
        for (int j = 0; j < NCLS; ++j) s += expf(h2[tid][j] - m);
        stats[tid][0] = m;
        stats[tid][1] = logf(s);
    }
    __syncthreads();

    #pragma unroll
    for (int p = 0; p < 5; ++p) {
        int o = p * 256 + tid;
        int r = o / NCLS, j = o - r * NCLS;
        int gr = rowBase + r;
        if (gr < M) out[(size_t)gr * NCLS + j] = h2[r][j] - stats[r][0] - stats[r][1];
    }
}

extern "C" void kernel_launch(void* const* d_in, const int* in_sizes, int n_in,
                              void* d_out, int out_size, void* d_ws, size_t ws_size,
                              hipStream_t stream) {
    const float* x  = (const float*)d_in[0];
    const int*   ei = (const int*)d_in[1];
    const float* W1 = (const float*)d_in[2];
    const float* b1 = (const float*)d_in[3];
    const float* W2 = (const float*)d_in[4];
    const float* b2 = (const float*)d_in[5];
    float* out = (float*)d_out;

    const int M = N_NODES;
    const int E = in_sizes[1] / 2;
    const int* src = ei;
    const int* dst = ei + E;

    // ---- workspace layout (peak 58.84 MB, matches round-3 proven bound) ----
    char* ws = (char*)d_ws;
    int*          cnt     = (int*)         (ws + 0);          // 400 KB
    float*        dinv    = (float*)       (ws + 409600);     // 400 KB
    int*          off     = (int*)         (ws + 819200);     // 400 KB + 4
    int*          part    = (int*)         (ws + 1232896);    // 392 B
    int*          bcur    = (int*)         (ws + 1236992);    // 3.1 KB
    int*          csr_src = (int*)         (ws + 1241088);    // 6.4 MB -> ends 7,641,088
    unsigned int* ebuf    = (unsigned int*)(ws + 7641088);    // 6.4 MB -> ends 14,041,088 (dead after sort)
    float*        h1      = (float*)       (ws + 7641088);    // ALIAS ebuf; 25.6 MB -> ends 33,241,088
    float*        z       = (float*)       (ws + 33241088);   // 25.6 MB -> ends 58,841,088
    float*        agg2    = h1;                               // alias: h1 dead after first agg

    const int nPart = (M + SCAN_ELEMS - 1) / SCAN_ELEMS;  // 98

    zero_kernel<<<(M + 255) / 256, 256, 0, stream>>>(cnt, M);
    count_deg_kernel<<<(E + 255) / 256, 256, 0, stream>>>(dst, cnt, E);
    make_dinv_kernel<<<(M + 255) / 256, 256, 0, stream>>>(cnt, dinv, M);

    scan_partial_kernel<<<nPart, 256, 0, stream>>>(cnt, part, M);
    scan_single_kernel<<<1, 128, 0, stream>>>(part, nPart);
    scan_final_kernel<<<nPart, 256, 0, stream>>>(cnt, part, off, M);
    init_bcur_kernel<<<(NBUCK + 255) / 256, 256, 0, stream>>>(off, bcur, NBUCK);

    scatter_bucket_kernel<<<(E + 255) / 256, 256, 0, stream>>>(src, dst, bcur, ebuf, E);
    sort_bucket_kernel<<<NBUCK, 256, 0, stream>>>(ebuf, off, csr_src, M);

    gemm1_kernel<<<(M + 63) / 64, 256, 0, stream>>>(x, W1, h1, M);

    agg_gather_kernel<true><<<(M + 3) / 4, 256, 0, stream>>>(h1, off, csr_src, dinv, b1, z, M);
    agg_gather_kernel<false><<<(M + 3) / 4, 256, 0, stream>>>(z, off, csr_src, dinv, nullptr, agg2, M);

    gemm2_lsm_kernel<<<(M + 31) / 32, 256, 0, stream>>>(agg2, W2, b2, out, M);
}

// Round 6
// 474.574 us; speedup vs baseline: 4.3417x; 1.5833x over previous
//
#include <hip/hip_runtime.h>
#include <hip/hip_bf16.h>
#include <cstddef>

#define N_NODES 100000
#define F_IN    512
#define HID     64
#define NCLS    40

#define BUCK_SZ   32
#define NBUCK     ((N_NODES + BUCK_SZ - 1) / BUCK_SZ)   // 3125
#define SRC_MASK  0x1FFFF                                // 17 bits
#define CUR_PAD   16                                     // ints: one cursor per 64B line

// ---------- utility ----------
__global__ void zero_kernel(int* __restrict__ p, int n) {
    int i = blockIdx.x * blockDim.x + threadIdx.x;
    if (i < n) p[i] = 0;
}

// ---------- degree / normalization ----------
__global__ void count_deg_kernel(const int* __restrict__ dst, int* __restrict__ cnt, int E) {
    int e = blockIdx.x * blockDim.x + threadIdx.x;
    if (e < E) atomicAdd(&cnt[dst[e]], 1);
}

__global__ void make_dinv_kernel(const int* __restrict__ cnt, float* __restrict__ dinv, int n) {
    int i = blockIdx.x * blockDim.x + threadIdx.x;
    if (i < n) dinv[i] = rsqrtf((float)(cnt[i] + 1));   // +1 self-loop
}

// ---------- exclusive scan (2-level) over degree counts ----------
#define SCAN_ELEMS 1024   // elements per block

__global__ __launch_bounds__(256) void scan_partial_kernel(const int* __restrict__ cnt,
                                                           int* __restrict__ part, int M) {
    __shared__ int sd[256];
    const int b = blockIdx.x, t = threadIdx.x;
    const int base = b * SCAN_ELEMS;
    int s = 0;
    for (int i = t; i < SCAN_ELEMS; i += 256) {
        int idx = base + i;
        s += (idx < M) ? cnt[idx] : 0;
    }
    sd[t] = s; __syncthreads();
    for (int d = 128; d > 0; d >>= 1) {
        if (t < d) sd[t] += sd[t + d];
        __syncthreads();
    }
    if (t == 0) part[b] = sd[0];
}

__global__ void scan_single_kernel(int* __restrict__ part, int n) {
    __shared__ int sd[128];
    int t = threadIdx.x;
    int v = (t < n) ? part[t] : 0;
    sd[t] = v; __syncthreads();
    for (int d = 1; d < 128; d <<= 1) {
        int u = (t >= d) ? sd[t - d] : 0;
        __syncthreads();
        sd[t] += u;
        __syncthreads();
    }
    if (t < n) part[t] = sd[t] - v;   // exclusive
}

__global__ __launch_bounds__(256) void scan_final_kernel(const int* __restrict__ cnt,
                                                         const int* __restrict__ part,
                                                         int* __restrict__ off, int M) {
    __shared__ int sd[256];
    const int b = blockIdx.x, t = threadIdx.x;
    const int base = b * SCAN_ELEMS + t * 4;
    int cs[4];
    #pragma unroll
    for (int i = 0; i < 4; ++i) cs[i] = (base + i < M) ? cnt[base + i] : 0;
    const int tot = cs[0] + cs[1] + cs[2] + cs[3];
    sd[t] = tot; __syncthreads();
    for (int d = 1; d < 256; d <<= 1) {
        int u = (t >= d) ? sd[t - d] : 0;
        __syncthreads();
        sd[t] += u;
        __syncthreads();
    }
    int run = sd[t] - tot + part[b];
    #pragma unroll
    for (int i = 0; i < 4; ++i) {
        if (base + i < M) off[base + i] = run;
        run += cs[i];
    }
    if (base < M && base + 4 >= M) off[M] = run;   // total (trailing cs are 0)
}

// ---------- bucket cursors (PADDED: one per 64B line): bcur[b*16] = off[b*BUCK_SZ]
__global__ void init_bcur_kernel(const int* __restrict__ off, int* __restrict__ bcur, int nb) {
    int i = blockIdx.x * blockDim.x + threadIdx.x;
    if (i < nb) bcur[i * CUR_PAD] = off[i * BUCK_SZ];
}

// ---------- phase 1: scatter edges into coarse dst-buckets ----------
__global__ void scatter_bucket_kernel(const int* __restrict__ src, const int* __restrict__ dst,
                                      int* __restrict__ bcur,
                                      unsigned int* __restrict__ ebuf, int E) {
    int e = blockIdx.x * blockDim.x + threadIdx.x;
    if (e < E) {
        int d = dst[e];
        int b = d / BUCK_SZ;
        int pos = atomicAdd(&bcur[b * CUR_PAD], 1);
        ebuf[pos] = (unsigned int)src[e] | ((unsigned int)(d & (BUCK_SZ - 1)) << 17);
    }
}

// ---------- phase 2: within-bucket counting place -> per-node CSR ----------
// bucket b's edges occupy [off[b*32], off[min(b*32+32,M)]) in BOTH ebuf
// (unordered) and csr_src (grouped by node) — writes stay in a ~4KB window.
__global__ __launch_bounds__(256) void sort_bucket_kernel(const unsigned int* __restrict__ ebuf,
                                                          const int* __restrict__ off,
                                                          int* __restrict__ csr_src, int M) {
    __shared__ int lcur[BUCK_SZ];
    const int b = blockIdx.x, t = threadIdx.x;
    const int base = b * BUCK_SZ;
    if (t < BUCK_SZ) {
        int node = base + t;
        lcur[t] = (node <= M) ? off[min(node, M)] : 0;
    }
    __syncthreads();
    const int e0 = off[min(base, M)];
    const int e1 = off[min(base + BUCK_SZ, M)];
    for (int e = e0 + t; e < e1; e += 256) {
        unsigned int pk = ebuf[e];
        int loc = pk >> 17;
        int pos = atomicAdd(&lcur[loc], 1);
        csr_src[pos] = (int)(pk & SRC_MASK);
    }
}

// ---------- GEMM1: H1 = X (Mx512) @ W1 (512x64) ----------
#define BK 32
__global__ __launch_bounds__(256) void gemm1_kernel(const float* __restrict__ X,
                                                    const float* __restrict__ W,
                                                    float* __restrict__ H,
                                                    int M) {
    __shared__ float As[BK][68];
    __shared__ float Bs[BK][64];

    const int tid = threadIdx.x;
    const int tx = tid & 15;
    const int ty = tid >> 4;
    const int rowBase = blockIdx.x * 64;

    const int a_row = tid >> 3;
    const int a_q   = tid & 7;
    const int b_row = tid >> 4;
    const int b_c4  = tid & 15;

    float acc[4][4] = {};

    for (int kt = 0; kt < F_IN; kt += BK) {
        #pragma unroll
        for (int h = 0; h < 2; ++h) {
            int r = a_row + h * 32;
            int gr = rowBase + r;
            if (gr >= M) gr = M - 1;
            const float4 v = *reinterpret_cast<const float4*>(
                &X[(size_t)gr * F_IN + kt + a_q * 4]);
            As[a_q * 4 + 0][r] = v.x;
            As[a_q * 4 + 1][r] = v.y;
            As[a_q * 4 + 2][r] = v.z;
            As[a_q * 4 + 3][r] = v.w;
        }
        #pragma unroll
        for (int h = 0; h < 2; ++h) {
            int kr = b_row + h * 16;
            const float4 v = *reinterpret_cast<const float4*>(
                &W[(size_t)(kt + kr) * 64 + b_c4 * 4]);
            *reinterpret_cast<float4*>(&Bs[kr][b_c4 * 4]) = v;
        }
        __syncthreads();

        #pragma unroll
        for (int k = 0; k < BK; ++k) {
            const float4 a = *reinterpret_cast<const float4*>(&As[k][ty * 4]);
            const float4 b = *reinterpret_cast<const float4*>(&Bs[k][tx * 4]);
            acc[0][0] += a.x * b.x; acc[0][1] += a.x * b.y; acc[0][2] += a.x * b.z; acc[0][3] += a.x * b.w;
            acc[1][0] += a.y * b.x; acc[1][1] += a.y * b.y; acc[1][2] += a.y * b.z; acc[1][3] += a.y * b.w;
            acc[2][0] += a.z * b.x; acc[2][1] += a.z * b.y; acc[2][2] += a.z * b.z; acc[2][3] += a.z * b.w;
            acc[3][0] += a.w * b.x; acc[3][1] += a.w * b.y; acc[3][2] += a.w * b.z; acc[3][3] += a.w * b.w;
        }
        __syncthreads();
    }

    #pragma unroll
    for (int i = 0; i < 4; ++i) {
        int gr = rowBase + ty * 4 + i;
        if (gr < M) {
            float4 v = make_float4(acc[i][0], acc[i][1], acc[i][2], acc[i][3]);
            *reinterpret_cast<float4*>(&H[(size_t)gr * HID + tx * 4]) = v;
        }
    }
}

// ---------- gather-based aggregation (one wave per node, width 64) ----------
template<bool RELU>
__global__ __launch_bounds__(256) void agg_gather_kernel(const float* __restrict__ h,
                                                         const int* __restrict__ off,
                                                         const int* __restrict__ csr_src,
                                                         const float* __restrict__ dinv,
                                                         const float* __restrict__ bias,
                                                         float* __restrict__ out, int M) {
    const int lane = threadIdx.x & 63;
    const int n = blockIdx.x * 4 + (threadIdx.x >> 6);
    if (n >= M) return;

    const float di = dinv[n];
    float acc = h[(size_t)n * HID + lane] * di * di;   // self-loop

    const int s0 = off[n], s1 = off[n + 1];
    for (int e = s0; e < s1; ) {
        int   s  = 0;
        float nm = 0.f;
        if (e + lane < s1) {
            s  = csr_src[e + lane];
            nm = dinv[s] * di;
        }
        const int cnt = min(64, s1 - e);
        int j = 0;
        for (; j + 4 <= cnt; j += 4) {
            int sa = __shfl(s, j);
            int sb = __shfl(s, j + 1);
            int sc = __shfl(s, j + 2);
            int sd = __shfl(s, j + 3);
            float na = __shfl(nm, j);
            float nb = __shfl(nm, j + 1);
            float nc = __shfl(nm, j + 2);
            float nd = __shfl(nm, j + 3);
            float va = h[(size_t)sa * HID + lane];
            float vb = h[(size_t)sb * HID + lane];
            float vc = h[(size_t)sc * HID + lane];
            float vd = h[(size_t)sd * HID + lane];
            acc = fmaf(va, na, acc);
            acc = fmaf(vb, nb, acc);
            acc = fmaf(vc, nc, acc);
            acc = fmaf(vd, nd, acc);
        }
        for (; j < cnt; ++j) {
            int sj = __shfl(s, j);
            float nj = __shfl(nm, j);
            acc = fmaf(h[(size_t)sj * HID + lane], nj, acc);
        }
        e += cnt;
    }

    if (RELU) acc = fmaxf(acc + bias[lane], 0.0f);
    out[(size_t)n * HID + lane] = acc;
}

// ---------- GEMM2 (64->40) + b2 + log_softmax, fused ----------
__global__ __launch_bounds__(256) void gemm2_lsm_kernel(const float* __restrict__ A,
                                                        const float* __restrict__ W,
                                                        const float* __restrict__ b2,
                                                        float* __restrict__ out, int M) {
    __shared__ float ws[HID * NCLS];     // 64x40
    __shared__ float hs[32][68];
    __shared__ float h2[32][NCLS];
    __shared__ float stats[32][2];

    const int tid = threadIdx.x;
    const int rowBase = blockIdx.x * 32;

    for (int i = tid; i < HID * NCLS; i += 256) ws[i] = W[i];

    #pragma unroll
    for (int p = 0; p < 2; ++p) {
        int i = p * 256 + tid;           // 32 rows x 16 float4
        int r = i >> 4, c4 = i & 15;
        int gr = rowBase + r;
        float4 v = make_float4(0.f, 0.f, 0.f, 0.f);
        if (gr < M) v = *reinterpret_cast<const float4*>(&A[(size_t)gr * HID + c4 * 4]);
        *reinterpret_cast<float4*>(&hs[r][c4 * 4]) = v;
    }
    __syncthreads();

    #pragma unroll
    for (int p = 0; p < 5; ++p) {
        int o = p * 256 + tid;           // 32 x 40 = 1280
        int r = o / NCLS, j = o - r * NCLS;
        float s = b2[j];
        #pragma unroll
        for (int k = 0; k < HID; ++k) s += hs[r][k] * ws[k * NCLS + j];
        h2[r][j] = s;
    }
    __syncthreads();

    if (tid < 32) {
        float m = -1e30f;
        #pragma unroll
        for (int j = 0; j < NCLS; ++j) m = fmaxf(m, h2[tid][j]);
        float s = 0.f;
        #pragma unroll
        for (int j = 0; j < NCLS; ++j) s += expf(h2[tid][j] - m);
        stats[tid][0] = m;
        stats[tid][1] = logf(s);
    }
    __syncthreads();

    #pragma unroll
    for (int p = 0; p < 5; ++p) {
        int o = p * 256 + tid;
        int r = o / NCLS, j = o - r * NCLS;
        int gr = rowBase + r;
        if (gr < M) out[(size_t)gr * NCLS + j] = h2[r][j] - stats[r][0] - stats[r][1];
    }
}

extern "C" void kernel_launch(void* const* d_in, const int* in_sizes, int n_in,
                              void* d_out, int out_size, void* d_ws, size_t ws_size,
                              hipStream_t stream) {
    const float* x  = (const float*)d_in[0];
    const int*   ei = (const int*)d_in[1];
    const float* W1 = (const float*)d_in[2];
    const float* b1 = (const float*)d_in[3];
    const float* W2 = (const float*)d_in[4];
    const float* b2 = (const float*)d_in[5];
    float* out = (float*)d_out;

    const int M = N_NODES;
    const int E = in_sizes[1] / 2;
    const int* src = ei;
    const int* dst = ei + E;

    // ---- workspace layout (peak 59.04 MB < 64 MiB; 58.84 MB proven, 67.6 MB crashed) ----
    char* ws = (char*)d_ws;
    int*          cnt     = (int*)         (ws + 0);          // 400 KB
    float*        dinv    = (float*)       (ws + 409600);     // 400 KB
    int*          off     = (int*)         (ws + 819200);     // 400 KB + 4
    int*          part    = (int*)         (ws + 1232896);    // 392 B
    int*          bcur    = (int*)         (ws + 1236992);    // 3125*64B = 200 KB -> ends 1,436,992
    int*          csr_src = (int*)         (ws + 1441792);    // 6.4 MB -> ends 7,841,792
    unsigned int* ebuf    = (unsigned int*)(ws + 7841792);    // 6.4 MB (dead after sort)
    float*        h1      = (float*)       (ws + 7841792);    // ALIAS ebuf; 25.6 MB -> ends 33,441,792
    float*        z       = (float*)       (ws + 33441792);   // 25.6 MB -> ends 59,041,792
    float*        agg2    = h1;                               // alias: h1 dead after first agg

    const int nPart = (M + SCAN_ELEMS - 1) / SCAN_ELEMS;  // 98

    zero_kernel<<<(M + 255) / 256, 256, 0, stream>>>(cnt, M);
    count_deg_kernel<<<(E + 255) / 256, 256, 0, stream>>>(dst, cnt, E);
    make_dinv_kernel<<<(M + 255) / 256, 256, 0, stream>>>(cnt, dinv, M);

    scan_partial_kernel<<<nPart, 256, 0, stream>>>(cnt, part, M);
    scan_single_kernel<<<1, 128, 0, stream>>>(part, nPart);
    scan_final_kernel<<<nPart, 256, 0, stream>>>(cnt, part, off, M);
    init_bcur_kernel<<<(NBUCK + 255) / 256, 256, 0, stream>>>(off, bcur, NBUCK);

    scatter_bucket_kernel<<<(E + 255) / 256, 256, 0, stream>>>(src, dst, bcur, ebuf, E);
    sort_bucket_kernel<<<NBUCK, 256, 0, stream>>>(ebuf, off, csr_src, M);

    gemm1_kernel<<<(M + 63) / 64, 256, 0, stream>>>(x, W1, h1, M);

    agg_gather_kernel<true><<<(M + 3) / 4, 256, 0, stream>>>(h1, off, csr_src, dinv, b1, z, M);
    agg_gather_kernel<false><<<(M + 3) / 4, 256, 0, stream>>>(z, off, csr_src, dinv, nullptr, agg2, M);

    gemm2_lsm_kernel<<<(M + 31) / 32, 256, 0, stream>>>(agg2, W2, b2, out, M);
}